// Round 1
// baseline (3728.172 us; speedup 1.0000x reference)
//
#include <hip/hip_runtime.h>
#include <hip/hip_bf16.h>

#define D 64

// ---------------------------------------------------------------------------
// out_init: out[g] = bout
// ---------------------------------------------------------------------------
__global__ void out_init_kernel(float* __restrict__ out, const float* __restrict__ bout, int G) {
    int i = blockIdx.x * blockDim.x + threadIdx.x;
    if (i < G) out[i] = bout[0];
}

// ---------------------------------------------------------------------------
// edge kernel: for each edge e, msg = relu(x[src] + edge_attr[e]); hbuf[dst] += msg
// thread t -> edge e = t>>4, quad q = (t&15)*4  (float4 per thread)
// ---------------------------------------------------------------------------
__global__ __launch_bounds__(256) void edge_kernel(
    const float* __restrict__ x, const float* __restrict__ ea,
    const int* __restrict__ ei, float* __restrict__ hbuf, int E)
{
    long long t = (long long)blockIdx.x * blockDim.x + threadIdx.x;
    int e = (int)(t >> 4);
    if (e >= E) return;
    int q = ((int)t & 15) << 2;

    int src = ei[e];
    int dst = ei[E + e];

    const float4 a  = *(const float4*)&ea[(size_t)e * D + q];
    const float4 xs = *(const float4*)&x[(size_t)src * D + q];

    float4 m;
    m.x = fmaxf(a.x + xs.x, 0.f);
    m.y = fmaxf(a.y + xs.y, 0.f);
    m.z = fmaxf(a.z + xs.z, 0.f);
    m.w = fmaxf(a.w + xs.w, 0.f);

    float* p = &hbuf[(size_t)dst * D + q];
    atomicAdd(p + 0, m.x);
    atomicAdd(p + 1, m.y);
    atomicAdd(p + 2, m.z);
    atomicAdd(p + 3, m.w);
}

// ---------------------------------------------------------------------------
// MLP kernel: one wave per node. Lane j holds W1[:,j] and W2[:,j] in VGPRs
// (64+64 regs, loaded once). Node row broadcast via wave-local LDS.
//   hidden = relu(h @ W1 + b1); r = relu(hidden @ W2 + b2)
// LAST=0: write r to xout.  LAST=1: s = dot(r, Wout); atomicAdd(out[batch[n]], s)
// ---------------------------------------------------------------------------
template <int LAST>
__global__ __launch_bounds__(256, 1) void mlp_kernel(
    const float* __restrict__ hin, float* __restrict__ xout,
    const float* __restrict__ W1, const float* __restrict__ b1,
    const float* __restrict__ W2, const float* __restrict__ b2,
    const int* __restrict__ batch, const float* __restrict__ Wout,
    float* __restrict__ out, int N)
{
    __shared__ __align__(16) float sh[4][D];
    __shared__ __align__(16) float sh2[4][D];

    const int lane = threadIdx.x & 63;
    const int wid  = threadIdx.x >> 6;

    float w1[D], w2[D];
#pragma unroll
    for (int k = 0; k < D; ++k) w1[k] = W1[k * D + lane];   // coalesced column load
#pragma unroll
    for (int k = 0; k < D; ++k) w2[k] = W2[k * D + lane];
    const float b1l = b1[lane];
    const float b2l = b2[lane];
    const float wo  = LAST ? Wout[lane] : 0.f;

    const int nwaves = gridDim.x * 4;
    for (int node = blockIdx.x * 4 + wid; node < N; node += nwaves) {
        float h = hin[(size_t)node * D + lane];
        sh[wid][lane] = h;

        float acc = b1l;
#pragma unroll
        for (int k = 0; k < D; k += 4) {
            float4 hk = *(const float4*)&sh[wid][k];   // broadcast read
            acc = fmaf(hk.x, w1[k + 0], acc);
            acc = fmaf(hk.y, w1[k + 1], acc);
            acc = fmaf(hk.z, w1[k + 2], acc);
            acc = fmaf(hk.w, w1[k + 3], acc);
        }
        float hid = fmaxf(acc, 0.f);
        sh2[wid][lane] = hid;

        float acc2 = b2l;
#pragma unroll
        for (int k = 0; k < D; k += 4) {
            float4 hk = *(const float4*)&sh2[wid][k];
            acc2 = fmaf(hk.x, w2[k + 0], acc2);
            acc2 = fmaf(hk.y, w2[k + 1], acc2);
            acc2 = fmaf(hk.z, w2[k + 2], acc2);
            acc2 = fmaf(hk.w, w2[k + 3], acc2);
        }
        float r = fmaxf(acc2, 0.f);

        if (LAST) {
            float s = r * wo;
#pragma unroll
            for (int off = 32; off; off >>= 1) s += __shfl_xor(s, off, 64);
            if (lane == 0) atomicAdd(&out[batch[node]], s);
        } else {
            xout[(size_t)node * D + lane] = r;
        }
    }
}

// ---------------------------------------------------------------------------
extern "C" void kernel_launch(void* const* d_in, const int* in_sizes, int n_in,
                              void* d_out, int out_size, void* d_ws, size_t ws_size,
                              hipStream_t stream) {
    const float* x    = (const float*)d_in[0];
    const int*   ei   = (const int*)d_in[1];
    const float* ea   = (const float*)d_in[2];
    const int*   batch= (const int*)d_in[3];
    const float* W1   = (const float*)d_in[4];
    const float* b1   = (const float*)d_in[5];
    const float* W2   = (const float*)d_in[6];
    const float* b2   = (const float*)d_in[7];
    const float* Wout = (const float*)d_in[8];
    const float* bout = (const float*)d_in[9];
    float* out = (float*)d_out;

    const int N = in_sizes[0] / D;     // 100000
    const int E = in_sizes[1] / 2;     // 1200000
    const int G = out_size;            // 128

    const size_t nodeBytes = (size_t)N * D * sizeof(float);
    float* bufA = (float*)d_ws;
    float* bufB = (float*)((char*)d_ws + nodeBytes);

    // out[g] = bout
    out_init_kernel<<<(G + 127) / 128, 128, 0, stream>>>(out, bout, G);

    const int edgeBlocks = (int)(((long long)E * 16 + 255) / 256);
    const int mlpBlocks  = 1024;

    // ---- layer 0: x_in -> bufA ----
    hipMemcpyAsync(bufA, x, nodeBytes, hipMemcpyDeviceToDevice, stream);
    edge_kernel<<<edgeBlocks, 256, 0, stream>>>(x, ea, ei, bufA, E);
    mlp_kernel<0><<<mlpBlocks, 256, 0, stream>>>(bufA, bufA,
        W1 + 0 * D * D, b1 + 0 * D, W2 + 0 * D * D, b2 + 0 * D,
        batch, Wout, out, N);

    // ---- layer 1: bufA -> bufB ----
    hipMemcpyAsync(bufB, bufA, nodeBytes, hipMemcpyDeviceToDevice, stream);
    edge_kernel<<<edgeBlocks, 256, 0, stream>>>(bufA, ea, ei, bufB, E);
    mlp_kernel<0><<<mlpBlocks, 256, 0, stream>>>(bufB, bufB,
        W1 + 1 * D * D, b1 + 1 * D, W2 + 1 * D * D, b2 + 1 * D,
        batch, Wout, out, N);

    // ---- layer 2: bufB -> bufA, fused pool + Wout ----
    hipMemcpyAsync(bufA, bufB, nodeBytes, hipMemcpyDeviceToDevice, stream);
    edge_kernel<<<edgeBlocks, 256, 0, stream>>>(bufB, ea, ei, bufA, E);
    mlp_kernel<1><<<mlpBlocks, 256, 0, stream>>>(bufA, nullptr,
        W1 + 2 * D * D, b1 + 2 * D, W2 + 2 * D * D, b2 + 2 * D,
        batch, Wout, out, N);
}

// Round 2
// 1376.831 us; speedup vs baseline: 2.7078x; 2.7078x over previous
//
#include <hip/hip_runtime.h>
#include <hip/hip_bf16.h>

#define D 64
#define CHUNK 32

// ---------------------------------------------------------------------------
__global__ void out_init_kernel(float* __restrict__ out, const float* __restrict__ bout, int G) {
    int i = blockIdx.x * blockDim.x + threadIdx.x;
    if (i < G) out[i] = bout[0];
}

// ---------------------------------------------------------------------------
// CSR build: histogram -> scan -> scatter  (rebuilt every call; graph shared
// by all 3 layers)
// ---------------------------------------------------------------------------
__global__ void deg_hist_kernel(const int* __restrict__ ei, int* __restrict__ deg, int E) {
    int e = blockIdx.x * blockDim.x + threadIdx.x;
    if (e < E) atomicAdd(&deg[ei[E + e]], 1);
}

__global__ __launch_bounds__(1024) void scan1_kernel(
    const int* __restrict__ deg, int* __restrict__ off, int* __restrict__ bsum, int N)
{
    __shared__ int sh[1024];
    int t = threadIdx.x;
    int i = blockIdx.x * 1024 + t;
    int v = (i < N) ? deg[i] : 0;
    sh[t] = v;
    __syncthreads();
#pragma unroll
    for (int o = 1; o < 1024; o <<= 1) {
        int u = (t >= o) ? sh[t - o] : 0;
        __syncthreads();
        sh[t] += u;
        __syncthreads();
    }
    if (i < N) off[i] = sh[t] - v;           // exclusive
    if (t == 1023) bsum[blockIdx.x] = sh[t]; // block total
}

__global__ __launch_bounds__(128) void scan2_kernel(
    const int* __restrict__ bsum, int* __restrict__ boff, int nb)
{
    __shared__ int sh[128];
    int t = threadIdx.x;
    int v = (t < nb) ? bsum[t] : 0;
    sh[t] = v;
    __syncthreads();
#pragma unroll
    for (int o = 1; o < 128; o <<= 1) {
        int u = (t >= o) ? sh[t - o] : 0;
        __syncthreads();
        sh[t] += u;
        __syncthreads();
    }
    if (t < nb) boff[t] = sh[t] - v;
}

__global__ void scan3_kernel(int* __restrict__ off, const int* __restrict__ boff, int N) {
    int i = blockIdx.x * blockDim.x + threadIdx.x;
    if (i < N) off[i] += boff[i >> 10];
}

__global__ void scatter_kernel(const int* __restrict__ ei, const int* __restrict__ off,
                               int* __restrict__ cur, int2* __restrict__ adj, int E)
{
    int e = blockIdx.x * blockDim.x + threadIdx.x;
    if (e >= E) return;
    int d = ei[E + e];
    int p = off[d] + atomicAdd(&cur[d], 1);
    adj[p] = make_int2(ei[e], e);   // (src, edge_id)
}

// ---------------------------------------------------------------------------
// Fused layer: one wave per CHUNK nodes. Gather-aggregate (no atomics) then
// register-resident MLP. LAST=1 fuses global_add_pool + Wout.
// ---------------------------------------------------------------------------
template <int LAST>
__global__ __launch_bounds__(256, 1) void layer_kernel(
    const float* __restrict__ xin, float* __restrict__ xout,
    const float* __restrict__ ea,
    const int2* __restrict__ adj, const int* __restrict__ off, const int* __restrict__ deg,
    const float* __restrict__ W1, const float* __restrict__ b1,
    const float* __restrict__ W2, const float* __restrict__ b2,
    const int* __restrict__ batch, const float* __restrict__ Wout,
    float* __restrict__ out, int N)
{
    __shared__ __align__(16) float sh[4][D];
    __shared__ __align__(16) float sh2[4][D];

    const int lane = threadIdx.x & 63;
    const int wid  = threadIdx.x >> 6;

    float w1[D], w2[D];
#pragma unroll
    for (int k = 0; k < D; ++k) w1[k] = W1[k * D + lane];
#pragma unroll
    for (int k = 0; k < D; ++k) w2[k] = W2[k * D + lane];
    const float b1l = b1[lane];
    const float b2l = b2[lane];
    const float wo  = LAST ? Wout[lane] : 0.f;

    const int wgi = blockIdx.x * 4 + wid;
    int n0 = wgi * CHUNK;
    if (n0 >= N) return;
    int n1 = min(n0 + CHUNK, N);

    float gsum = 0.f;
    int   curg = -1;

    for (int n = n0; n < n1; ++n) {
        // ---- gather-aggregate: h = x[n] + sum relu(x[src] + ea[e]) ----
        float acc = xin[(size_t)n * D + lane];
        int p  = off[n];
        int pe = p + deg[n];
        for (; p + 1 < pe; p += 2) {
            int2 a0 = adj[p];
            int2 a1 = adj[p + 1];
            float x0 = xin[(size_t)a0.x * D + lane];
            float e0 = ea [(size_t)a0.y * D + lane];
            float x1 = xin[(size_t)a1.x * D + lane];
            float e1 = ea [(size_t)a1.y * D + lane];
            acc += fmaxf(x0 + e0, 0.f) + fmaxf(x1 + e1, 0.f);
        }
        if (p < pe) {
            int2 a0 = adj[p];
            acc += fmaxf(xin[(size_t)a0.x * D + lane] + ea[(size_t)a0.y * D + lane], 0.f);
        }

        // ---- MLP: relu(relu(h@W1+b1)@W2+b2) ----
        sh[wid][lane] = acc;
        float t1 = b1l;
#pragma unroll
        for (int k = 0; k < D; k += 4) {
            float4 hk = *(const float4*)&sh[wid][k];   // wave-local broadcast
            t1 = fmaf(hk.x, w1[k + 0], t1);
            t1 = fmaf(hk.y, w1[k + 1], t1);
            t1 = fmaf(hk.z, w1[k + 2], t1);
            t1 = fmaf(hk.w, w1[k + 3], t1);
        }
        float hid = fmaxf(t1, 0.f);
        sh2[wid][lane] = hid;

        float t2 = b2l;
#pragma unroll
        for (int k = 0; k < D; k += 4) {
            float4 hk = *(const float4*)&sh2[wid][k];
            t2 = fmaf(hk.x, w2[k + 0], t2);
            t2 = fmaf(hk.y, w2[k + 1], t2);
            t2 = fmaf(hk.z, w2[k + 2], t2);
            t2 = fmaf(hk.w, w2[k + 3], t2);
        }
        float r = fmaxf(t2, 0.f);

        if (LAST) {
            float s = r * wo;
#pragma unroll
            for (int o = 32; o; o >>= 1) s += __shfl_xor(s, o, 64);
            int g = batch[n];                       // batch sorted -> near-uniform runs
            if (g != curg) {
                if (curg >= 0 && lane == 0) atomicAdd(&out[curg], gsum);
                curg = g;
                gsum = s;
            } else {
                gsum += s;
            }
        } else {
            xout[(size_t)n * D + lane] = r;
        }
    }
    if (LAST && curg >= 0 && lane == 0) atomicAdd(&out[curg], gsum);
}

// ---------------------------------------------------------------------------
extern "C" void kernel_launch(void* const* d_in, const int* in_sizes, int n_in,
                              void* d_out, int out_size, void* d_ws, size_t ws_size,
                              hipStream_t stream) {
    const float* x     = (const float*)d_in[0];
    const int*   ei    = (const int*)d_in[1];
    const float* ea    = (const float*)d_in[2];
    const int*   batch = (const int*)d_in[3];
    const float* W1    = (const float*)d_in[4];
    const float* b1    = (const float*)d_in[5];
    const float* W2    = (const float*)d_in[6];
    const float* b2    = (const float*)d_in[7];
    const float* Wout  = (const float*)d_in[8];
    const float* bout  = (const float*)d_in[9];
    float* out = (float*)d_out;

    const int N = in_sizes[0] / D;   // 100000
    const int E = in_sizes[1] / 2;   // 1200000
    const int G = out_size;          // 128

    // ---- workspace layout ----
    char* w = (char*)d_ws;
    const size_t nodeBytes = (size_t)N * D * sizeof(float);
    float* ping  = (float*)w;                 w += nodeBytes;
    float* pong  = (float*)w;                 w += nodeBytes;
    int2*  adj   = (int2*)w;                  w += (size_t)E * sizeof(int2);
    int*   deg   = (int*)w;                   w += (size_t)N * sizeof(int);
    int*   off   = (int*)w;                   w += (size_t)N * sizeof(int);
    int*   cur   = (int*)w;                   w += (size_t)N * sizeof(int);
    int*   bsum  = (int*)w;                   w += 128 * sizeof(int);
    int*   boff  = (int*)w;                   w += 128 * sizeof(int);

    const int nScanBlocks = (N + 1023) / 1024;          // 98
    const int edgeBlocks  = (E + 255) / 256;
    const int nWaves      = (N + CHUNK - 1) / CHUNK;    // 3125
    const int layerBlocks = (nWaves + 3) / 4;           // 782

    // ---- out = bout ----
    out_init_kernel<<<(G + 127) / 128, 128, 0, stream>>>(out, bout, G);

    // ---- CSR build (once; shared by all layers) ----
    hipMemsetAsync(deg, 0, (size_t)N * sizeof(int), stream);
    hipMemsetAsync(cur, 0, (size_t)N * sizeof(int), stream);
    deg_hist_kernel<<<edgeBlocks, 256, 0, stream>>>(ei, deg, E);
    scan1_kernel<<<nScanBlocks, 1024, 0, stream>>>(deg, off, bsum, N);
    scan2_kernel<<<1, 128, 0, stream>>>(bsum, boff, nScanBlocks);
    scan3_kernel<<<(N + 255) / 256, 256, 0, stream>>>(off, boff, N);
    scatter_kernel<<<edgeBlocks, 256, 0, stream>>>(ei, off, cur, adj, E);

    // ---- 3 fused layers ----
    layer_kernel<0><<<layerBlocks, 256, 0, stream>>>(x, ping, ea, adj, off, deg,
        W1 + 0 * D * D, b1 + 0 * D, W2 + 0 * D * D, b2 + 0 * D, batch, Wout, out, N);
    layer_kernel<0><<<layerBlocks, 256, 0, stream>>>(ping, pong, ea, adj, off, deg,
        W1 + 1 * D * D, b1 + 1 * D, W2 + 1 * D * D, b2 + 1 * D, batch, Wout, out, N);
    layer_kernel<1><<<layerBlocks, 256, 0, stream>>>(pong, nullptr, ea, adj, off, deg,
        W1 + 2 * D * D, b1 + 2 * D, W2 + 2 * D * D, b2 + 2 * D, batch, Wout, out, N);
}

// Round 3
// 641.671 us; speedup vs baseline: 5.8101x; 2.1457x over previous
//
#include <hip/hip_runtime.h>
#include <hip/hip_bf16.h>

#define D 64

// ---------------------------------------------------------------------------
__global__ void out_init_kernel(float* __restrict__ out, const float* __restrict__ bout, int G) {
    int i = blockIdx.x * blockDim.x + threadIdx.x;
    if (i < G) out[i] = bout[0];
}

// ---------------------------------------------------------------------------
// CSR build: histogram -> scan -> scatter
// ---------------------------------------------------------------------------
__global__ void deg_hist_kernel(const int* __restrict__ ei, int* __restrict__ deg, int E) {
    int e = blockIdx.x * blockDim.x + threadIdx.x;
    if (e < E) atomicAdd(&deg[ei[E + e]], 1);
}

__global__ __launch_bounds__(1024) void scan1_kernel(
    const int* __restrict__ deg, int* __restrict__ off, int* __restrict__ bsum, int N)
{
    __shared__ int sh[1024];
    int t = threadIdx.x;
    int i = blockIdx.x * 1024 + t;
    int v = (i < N) ? deg[i] : 0;
    sh[t] = v;
    __syncthreads();
#pragma unroll
    for (int o = 1; o < 1024; o <<= 1) {
        int u = (t >= o) ? sh[t - o] : 0;
        __syncthreads();
        sh[t] += u;
        __syncthreads();
    }
    if (i < N) off[i] = sh[t] - v;
    if (t == 1023) bsum[blockIdx.x] = sh[t];
}

__global__ __launch_bounds__(128) void scan2_kernel(
    const int* __restrict__ bsum, int* __restrict__ boff, int nb)
{
    __shared__ int sh[128];
    int t = threadIdx.x;
    int v = (t < nb) ? bsum[t] : 0;
    sh[t] = v;
    __syncthreads();
#pragma unroll
    for (int o = 1; o < 128; o <<= 1) {
        int u = (t >= o) ? sh[t - o] : 0;
        __syncthreads();
        sh[t] += u;
        __syncthreads();
    }
    if (t < nb) boff[t] = sh[t] - v;
}

__global__ void scan3_kernel(int* __restrict__ off, const int* __restrict__ boff, int N) {
    int i = blockIdx.x * blockDim.x + threadIdx.x;
    if (i < N) off[i] += boff[i >> 10];
}

__global__ void scatter_kernel(const int* __restrict__ ei, const int* __restrict__ off,
                               int* __restrict__ cur, int2* __restrict__ adj, int E)
{
    int e = blockIdx.x * blockDim.x + threadIdx.x;
    if (e >= E) return;
    int d = ei[E + e];
    int p = off[d] + atomicAdd(&cur[d], 1);
    adj[p] = make_int2(ei[e], e);
}

// ---------------------------------------------------------------------------
// aggregate: one wave per node.  h[n] = x[n] + sum_e relu(x[src] + ea[e])
// 4-edge unroll, 4 independent accumulators. Low VGPR -> 8 waves/SIMD.
// ---------------------------------------------------------------------------
__global__ __launch_bounds__(256) void aggregate_kernel(
    const float* __restrict__ xin, const float* __restrict__ ea,
    const int2* __restrict__ adj, const int* __restrict__ off,
    const int* __restrict__ deg, float* __restrict__ h, int N)
{
    const int lane = threadIdx.x & 63;
    const int n    = (blockIdx.x << 2) + (threadIdx.x >> 6);
    if (n >= N) return;

    float self = xin[(size_t)n * D + lane];   // issue early
    int p  = off[n];
    const int pe = p + deg[n];

    float a0 = 0.f, a1 = 0.f, a2 = 0.f, a3 = 0.f;
    for (; p + 3 < pe; p += 4) {
        int2 e0 = adj[p];
        int2 e1 = adj[p + 1];
        int2 e2 = adj[p + 2];
        int2 e3 = adj[p + 3];
        float x0 = xin[(size_t)e0.x * D + lane];
        float q0 = ea [(size_t)e0.y * D + lane];
        float x1 = xin[(size_t)e1.x * D + lane];
        float q1 = ea [(size_t)e1.y * D + lane];
        float x2 = xin[(size_t)e2.x * D + lane];
        float q2 = ea [(size_t)e2.y * D + lane];
        float x3 = xin[(size_t)e3.x * D + lane];
        float q3 = ea [(size_t)e3.y * D + lane];
        a0 += fmaxf(x0 + q0, 0.f);
        a1 += fmaxf(x1 + q1, 0.f);
        a2 += fmaxf(x2 + q2, 0.f);
        a3 += fmaxf(x3 + q3, 0.f);
    }
    for (; p < pe; ++p) {
        int2 e0 = adj[p];
        a0 += fmaxf(xin[(size_t)e0.x * D + lane] + ea[(size_t)e0.y * D + lane], 0.f);
    }

    h[(size_t)n * D + lane] = self + ((a0 + a1) + (a2 + a3));
}

// ---------------------------------------------------------------------------
// MLP: relu(relu(h@W1+b1)@W2+b2).  Lane j holds W1[:,j], W2[:,j] pinned in
// VGPRs (asm barrier prevents the compiler sinking the loads into the loop).
// 4 partial accumulators break the dependent-FMA chain. Wave-local LDS
// broadcast for the node row; no block barriers needed (wave-synchronous).
// LAST=1: fuse global_add_pool + Wout (batch is sorted -> run-length pooling).
// ---------------------------------------------------------------------------
template <int LAST>
__global__ __launch_bounds__(256, 1) void mlp_kernel(
    const float* __restrict__ hin, float* __restrict__ xout,
    const float* __restrict__ W1, const float* __restrict__ b1,
    const float* __restrict__ W2, const float* __restrict__ b2,
    const int* __restrict__ batch, const float* __restrict__ Wout,
    float* __restrict__ out, int N, int chunk)
{
    __shared__ __align__(16) float sh[4][D];
    __shared__ __align__(16) float sh2[4][D];

    const int lane = threadIdx.x & 63;
    const int wid  = threadIdx.x >> 6;

    float w1[D], w2[D];
#pragma unroll
    for (int k = 0; k < D; ++k) w1[k] = W1[k * D + lane];
#pragma unroll
    for (int k = 0; k < D; ++k) w2[k] = W2[k * D + lane];
#pragma unroll
    for (int k = 0; k < D; ++k) { asm volatile("" : "+v"(w1[k])); asm volatile("" : "+v"(w2[k])); }
    const float b1l = b1[lane];
    const float b2l = b2[lane];
    const float wo  = LAST ? Wout[lane] : 0.f;

    const int w = (blockIdx.x << 2) + wid;
    int n0 = w * chunk;
    if (n0 >= N) return;
    int n1 = min(n0 + chunk, N);

    float gsum = 0.f;
    int   curg = -1;

    for (int n = n0; n < n1; ++n) {
        float hv = hin[(size_t)n * D + lane];
        sh[wid][lane] = hv;

        float t0 = 0.f, t1 = 0.f, t2 = 0.f, t3 = 0.f;
#pragma unroll
        for (int k = 0; k < D; k += 4) {
            float4 hk = *(const float4*)&sh[wid][k];   // uniform-address broadcast
            t0 = fmaf(hk.x, w1[k + 0], t0);
            t1 = fmaf(hk.y, w1[k + 1], t1);
            t2 = fmaf(hk.z, w1[k + 2], t2);
            t3 = fmaf(hk.w, w1[k + 3], t3);
        }
        float hid = fmaxf(((t0 + t1) + (t2 + t3)) + b1l, 0.f);
        sh2[wid][lane] = hid;

        float s0 = 0.f, s1 = 0.f, s2 = 0.f, s3 = 0.f;
#pragma unroll
        for (int k = 0; k < D; k += 4) {
            float4 hk = *(const float4*)&sh2[wid][k];
            s0 = fmaf(hk.x, w2[k + 0], s0);
            s1 = fmaf(hk.y, w2[k + 1], s1);
            s2 = fmaf(hk.z, w2[k + 2], s2);
            s3 = fmaf(hk.w, w2[k + 3], s3);
        }
        float r = fmaxf(((s0 + s1) + (s2 + s3)) + b2l, 0.f);

        if (LAST) {
            float s = r * wo;
#pragma unroll
            for (int o = 32; o; o >>= 1) s += __shfl_xor(s, o, 64);
            int g = batch[n];
            if (g != curg) {
                if (curg >= 0 && lane == 0) atomicAdd(&out[curg], gsum);
                curg = g;
                gsum = s;
            } else {
                gsum += s;
            }
        } else {
            xout[(size_t)n * D + lane] = r;
        }
    }
    if (LAST && curg >= 0 && lane == 0) atomicAdd(&out[curg], gsum);
}

// ---------------------------------------------------------------------------
extern "C" void kernel_launch(void* const* d_in, const int* in_sizes, int n_in,
                              void* d_out, int out_size, void* d_ws, size_t ws_size,
                              hipStream_t stream) {
    const float* x     = (const float*)d_in[0];
    const int*   ei    = (const int*)d_in[1];
    const float* ea    = (const float*)d_in[2];
    const int*   batch = (const int*)d_in[3];
    const float* W1    = (const float*)d_in[4];
    const float* b1    = (const float*)d_in[5];
    const float* W2    = (const float*)d_in[6];
    const float* b2    = (const float*)d_in[7];
    const float* Wout  = (const float*)d_in[8];
    const float* bout  = (const float*)d_in[9];
    float* out = (float*)d_out;

    const int N = in_sizes[0] / D;   // 100000
    const int E = in_sizes[1] / 2;   // 1200000
    const int G = out_size;          // 128

    // ---- workspace layout ----
    char* w = (char*)d_ws;
    const size_t nodeBytes = (size_t)N * D * sizeof(float);
    float* bufA  = (float*)w;                 w += nodeBytes;
    float* bufB  = (float*)w;                 w += nodeBytes;
    int2*  adj   = (int2*)w;                  w += (size_t)E * sizeof(int2);
    int*   deg   = (int*)w;                   w += (size_t)N * sizeof(int);
    int*   off   = (int*)w;                   w += (size_t)N * sizeof(int);
    int*   cur   = (int*)w;                   w += (size_t)N * sizeof(int);
    int*   bsum  = (int*)w;                   w += 128 * sizeof(int);
    int*   boff  = (int*)w;                   w += 128 * sizeof(int);

    const int nScanBlocks = (N + 1023) / 1024;
    const int edgeBlocks  = (E + 255) / 256;
    const int aggBlocks   = (N + 3) / 4;          // one wave per node

    const int mlpWaves  = 4096;
    const int mlpBlocks = mlpWaves / 4;
    const int chunk     = (N + mlpWaves - 1) / mlpWaves;   // 25

    out_init_kernel<<<(G + 127) / 128, 128, 0, stream>>>(out, bout, G);

    // ---- CSR build (shared by all layers) ----
    hipMemsetAsync(deg, 0, (size_t)N * sizeof(int), stream);
    hipMemsetAsync(cur, 0, (size_t)N * sizeof(int), stream);
    deg_hist_kernel<<<edgeBlocks, 256, 0, stream>>>(ei, deg, E);
    scan1_kernel<<<nScanBlocks, 1024, 0, stream>>>(deg, off, bsum, N);
    scan2_kernel<<<1, 128, 0, stream>>>(bsum, boff, nScanBlocks);
    scan3_kernel<<<(N + 255) / 256, 256, 0, stream>>>(off, boff, N);
    scatter_kernel<<<edgeBlocks, 256, 0, stream>>>(ei, off, cur, adj, E);

    // ---- layer 0: x -> bufA ----
    aggregate_kernel<<<aggBlocks, 256, 0, stream>>>(x, ea, adj, off, deg, bufA, N);
    mlp_kernel<0><<<mlpBlocks, 256, 0, stream>>>(bufA, bufA,
        W1 + 0 * D * D, b1 + 0 * D, W2 + 0 * D * D, b2 + 0 * D, batch, Wout, out, N, chunk);

    // ---- layer 1: bufA -> bufB ----
    aggregate_kernel<<<aggBlocks, 256, 0, stream>>>(bufA, ea, adj, off, deg, bufB, N);
    mlp_kernel<0><<<mlpBlocks, 256, 0, stream>>>(bufB, bufB,
        W1 + 1 * D * D, b1 + 1 * D, W2 + 1 * D * D, b2 + 1 * D, batch, Wout, out, N, chunk);

    // ---- layer 2: bufB -> bufA (h), fused pool + Wout ----
    aggregate_kernel<<<aggBlocks, 256, 0, stream>>>(bufB, ea, adj, off, deg, bufA, N);
    mlp_kernel<1><<<mlpBlocks, 256, 0, stream>>>(bufA, nullptr,
        W1 + 2 * D * D, b1 + 2 * D, W2 + 2 * D * D, b2 + 2 * D, batch, Wout, out, N, chunk);
}